// Round 1
// baseline (79622.363 us; speedup 1.0000x reference)
//
#include <hip/hip_runtime.h>

#define L 64
#define TLEN 200000
#define CH 512
#define NCH 391                       // ceil(200000/512)
#define LASTLEN (TLEN - (NCH - 1) * CH)   // 320
#define NEGV -10000.0f
#define STARTT 62
#define STOPT 63

// workspace layout (bytes)
#define CKPT_OFF 0                          // float[(NCH+1)*L]  = 100352 B
#define M_OFF ((NCH + 1) * L * 4)           // uchar[NCH*L]      = 25024 B
#define ETAG_OFF (M_OFF + NCH * L)          // int[NCH]          = 1564 B  (offset 125376, 4-aligned)

// ---------------------------------------------------------------------------
// helpers
// ---------------------------------------------------------------------------
__device__ __forceinline__ void load_trow(const float* __restrict__ trans, int n, float* trow) {
#pragma unroll
    for (int i = 0; i < 16; ++i) {
        const float4 q = reinterpret_cast<const float4*>(trans)[n * 16 + i];
        trow[4 * i + 0] = q.x;
        trow[4 * i + 1] = q.y;
        trow[4 * i + 2] = q.z;
        trow[4 * i + 3] = q.w;
    }
}

// Bit-exact chunk replay from checkpoint; records backpointers into LDS.
// Single wave per block. One barrier per step (after the vsh write): within a
// wave, program order guarantees all broadcast reads of iteration i precede
// the write; the barrier makes the write visible and fences the compiler.
__device__ __forceinline__ void replay_chunk(const float* __restrict__ feats,
                                             const float* __restrict__ ckpt,
                                             const float* trow, float* vsh,
                                             unsigned char* bpl, int c, int len, int n) {
    float vreg = ckpt[c * L + n];
    vsh[n] = vreg;
    __syncthreads();
    const int base = c * CH;

    float fc[8];
#pragma unroll
    for (int j = 0; j < 8; ++j) fc[j] = feats[(base + j) * L + n];

    for (int sb = 0; sb < len; sb += 8) {
        float fn_[8];
        const bool more = (sb + 8) < len;
        if (more) {
#pragma unroll
            for (int j = 0; j < 8; ++j) fn_[j] = feats[(base + sb + 8 + j) * L + n];
        }
#pragma unroll
        for (int j = 0; j < 8; ++j) {
            // argmax over p with first-max (strictly-greater) semantics,
            // 4 independent chains of 16, merged in ascending order.
            float mc[4];
            int ic[4];
#pragma unroll
            for (int g = 0; g < 4; ++g) {
                float m = -INFINITY;
                int idx = g * 16;
#pragma unroll
                for (int r = 0; r < 4; ++r) {
                    const int pb = g * 16 + r * 4;
                    const float4 vv = *reinterpret_cast<const float4*>(vsh + pb);
                    const float a = vv.x + trow[pb + 0];
                    const float b = vv.y + trow[pb + 1];
                    const float cc = vv.z + trow[pb + 2];
                    const float d = vv.w + trow[pb + 3];
                    if (a > m)  { m = a;  idx = pb + 0; }
                    if (b > m)  { m = b;  idx = pb + 1; }
                    if (cc > m) { m = cc; idx = pb + 2; }
                    if (d > m)  { m = d;  idx = pb + 3; }
                }
                mc[g] = m;
                ic[g] = idx;
            }
            float m = mc[0];
            int idx = ic[0];
            if (mc[1] > m) { m = mc[1]; idx = ic[1]; }
            if (mc[2] > m) { m = mc[2]; idx = ic[2]; }
            if (mc[3] > m) { m = mc[3]; idx = ic[3]; }

            vreg = m + fc[j];
            bpl[(sb + j) * L + n] = (unsigned char)idx;
            vsh[n] = vreg;
            __syncthreads();
        }
        if (more) {
#pragma unroll
            for (int j = 0; j < 8; ++j) fc[j] = fn_[j];
        }
    }
}

// ---------------------------------------------------------------------------
// Pass 1: exact sequential forward recurrence (the critical path).
// Single wave; no backpointers; checkpoints v_{t-1} every CH steps.
// ---------------------------------------------------------------------------
__global__ __launch_bounds__(64) void k_forward(const float* __restrict__ feats,
                                                const float* __restrict__ trans,
                                                float* __restrict__ ckpt) {
    const int n = threadIdx.x;
    float trow[L];
    load_trow(trans, n, trow);

    __shared__ __align__(16) float vsh[L];
    float vreg = (n == STARTT) ? 0.0f : NEGV;
    vsh[n] = vreg;
    __syncthreads();

    float fc[8];
#pragma unroll
    for (int j = 0; j < 8; ++j) fc[j] = feats[j * L + n];

    for (int tb = 0; tb < TLEN; tb += 8) {
        if ((tb & (CH - 1)) == 0) ckpt[(tb >> 9) * L + n] = vreg;  // v_{tb-1}

        float fn_[8];
        const bool more = (tb + 8) < TLEN;
        if (more) {
#pragma unroll
            for (int j = 0; j < 8; ++j) fn_[j] = feats[(tb + 8 + j) * L + n];
        }
#pragma unroll
        for (int j = 0; j < 8; ++j) {
            float mg[4];
#pragma unroll
            for (int g = 0; g < 4; ++g) {
                float mm = -INFINITY;
#pragma unroll
                for (int r = 0; r < 4; ++r) {
                    const int pb = g * 16 + r * 4;
                    const float4 vv = *reinterpret_cast<const float4*>(vsh + pb);
                    const float a = vv.x + trow[pb + 0];
                    const float b = vv.y + trow[pb + 1];
                    const float cc = vv.z + trow[pb + 2];
                    const float d = vv.w + trow[pb + 3];
                    mm = fmaxf(mm, fmaxf(fmaxf(a, b), fmaxf(cc, d)));
                }
                mg[g] = mm;
            }
            const float mx = fmaxf(fmaxf(mg[0], mg[1]), fmaxf(mg[2], mg[3]));
            vreg = mx + fc[j];
            vsh[n] = vreg;
            __syncthreads();
        }
        if (more) {
#pragma unroll
            for (int j = 0; j < 8; ++j) fc[j] = fn_[j];
        }
    }
    ckpt[NCH * L + n] = vreg;  // v_{T-1}
}

// ---------------------------------------------------------------------------
// Pass 2: per-chunk bit-exact replay -> backpointers -> 64-entry chunk map.
// M[c*64+e] = tag at (c*CH - 1) given tag e at the last step of chunk c.
// ---------------------------------------------------------------------------
__global__ __launch_bounds__(64) void k_maps(const float* __restrict__ feats,
                                             const float* __restrict__ trans,
                                             const float* __restrict__ ckpt,
                                             unsigned char* __restrict__ M) {
    const int c = blockIdx.x;
    const int n = threadIdx.x;
    const int len = (c == NCH - 1) ? LASTLEN : CH;

    __shared__ __align__(16) float vsh[L];
    __shared__ unsigned char bpl[CH * L];

    float trow[L];
    load_trow(trans, n, trow);
    replay_chunk(feats, ckpt, trow, vsh, bpl, c, len, n);
    __syncthreads();

    int tag = n;
    for (int s = len - 1; s >= 0; --s) tag = bpl[s * L + tag];
    M[c * L + n] = (unsigned char)tag;
}

// ---------------------------------------------------------------------------
// Pass 3: terminal argmax (bit-exact score) + back-to-front map composition.
// ---------------------------------------------------------------------------
__global__ __launch_bounds__(64) void k_stitch(const float* __restrict__ trans,
                                               const float* __restrict__ ckpt,
                                               const unsigned char* __restrict__ M,
                                               int* __restrict__ etag,
                                               float* __restrict__ out) {
    const int n = threadIdx.x;
    __shared__ float tsh[L];
    __shared__ int bsh;
    __shared__ __align__(16) unsigned char msh[NCH * L];

    tsh[n] = ckpt[NCH * L + n] + trans[STOPT * L + n];  // terminal[n]
    __syncthreads();
    if (n == 0) {
        float m = tsh[0];
        int b = 0;
        for (int p = 1; p < L; ++p)
            if (tsh[p] > m) { m = tsh[p]; b = p; }  // first-max, like jnp.argmax
        out[0] = m;   // path_score, bit-exact
        bsh = b;
    }
    __syncthreads();

    for (int i = n; i < (NCH * L) / 4; i += L)
        reinterpret_cast<int*>(msh)[i] = reinterpret_cast<const int*>(M)[i];
    __syncthreads();

    if (n == 0) {
        int carry = bsh;  // tag at t = T-1 = end of chunk NCH-1
        for (int c = NCH - 1; c >= 1; --c) {
            etag[c] = carry;
            carry = msh[c * L + carry];
        }
        etag[0] = carry;
    }
}

// ---------------------------------------------------------------------------
// Pass 4: per-chunk replay again, walk backwards from etag[c], emit path.
// Path written as float32 (harness reads the concatenated output as float).
// ---------------------------------------------------------------------------
__global__ __launch_bounds__(64) void k_emit(const float* __restrict__ feats,
                                             const float* __restrict__ trans,
                                             const float* __restrict__ ckpt,
                                             const int* __restrict__ etag,
                                             float* __restrict__ out) {
    const int c = blockIdx.x;
    const int n = threadIdx.x;
    const int len = (c == NCH - 1) ? LASTLEN : CH;

    __shared__ __align__(16) float vsh[L];
    __shared__ unsigned char bpl[CH * L];
    __shared__ unsigned char plc[CH];

    float trow[L];
    load_trow(trans, n, trow);
    replay_chunk(feats, ckpt, trow, vsh, bpl, c, len, n);
    __syncthreads();

    int tag = etag[c];  // uniform; bpl reads below broadcast (same address)
    for (int s = len - 1; s >= 0; --s) {
        if (n == 0) plc[s] = (unsigned char)tag;
        tag = bpl[s * L + tag];
    }
    __syncthreads();

    for (int i = n; i < len; i += L)
        out[1 + c * CH + i] = (float)plc[i];
}

// ---------------------------------------------------------------------------
extern "C" void kernel_launch(void* const* d_in, const int* in_sizes, int n_in,
                              void* d_out, int out_size, void* d_ws, size_t ws_size,
                              hipStream_t stream) {
    const float* feats = (const float*)d_in[0];   // (1, T, L) fp32
    const float* trans = (const float*)d_in[1];   // (L, L) fp32
    float* out = (float*)d_out;                   // [score, path(T) as float]
    char* ws = (char*)d_ws;
    float* ckpt = (float*)(ws + CKPT_OFF);
    unsigned char* M = (unsigned char*)(ws + M_OFF);
    int* etag = (int*)(ws + ETAG_OFF);

    hipLaunchKernelGGL(k_forward, dim3(1), dim3(64), 0, stream, feats, trans, ckpt);
    hipLaunchKernelGGL(k_maps, dim3(NCH), dim3(64), 0, stream, feats, trans, ckpt, M);
    hipLaunchKernelGGL(k_stitch, dim3(1), dim3(64), 0, stream, trans, ckpt, M, etag, out);
    hipLaunchKernelGGL(k_emit, dim3(NCH), dim3(64), 0, stream, feats, trans, ckpt, etag, out);
}

// Round 2
// 66202.979 us; speedup vs baseline: 1.2027x; 1.2027x over previous
//
#include <hip/hip_runtime.h>

#define L 64
#define TLEN 200000
#define CH 512
#define NCH 391                       // ceil(200000/512)
#define LASTLEN (TLEN - (NCH - 1) * CH)   // 320
#define NEGV -10000.0f
#define STARTT 62
#define STOPT 63

// workspace layout (bytes)
#define CKPT_OFF 0                          // float[(NCH+1)*L]  = 100352 B
#define M_OFF ((NCH + 1) * L * 4)           // uchar[NCH*L]      = 25024 B
#define ETAG_OFF (M_OFF + NCH * L)          // int[NCH]

typedef float f32x4 __attribute__((ext_vector_type(4)));

// ---------------------------------------------------------------------------
// forward-step group macros: 4 candidates (adds as an f32x4 vector op so the
// backend can select v_pk_add_f32), max tree shaped for v_max3_f32 selection.
// ---------------------------------------------------------------------------
#define GRP0(qq, base)                                                        \
    ({                                                                        \
        const f32x4 va_ = *reinterpret_cast<const f32x4*>(vsh + (base));      \
        const f32x4 s_ = va_ + (qq);                                          \
        fmaxf(fmaxf(s_.x, s_.y), fmaxf(s_.z, s_.w));                          \
    })

#define GRPA(acc, qq, base)                                                   \
    do {                                                                      \
        const f32x4 va_ = *reinterpret_cast<const f32x4*>(vsh + (base));      \
        const f32x4 s_ = va_ + (qq);                                          \
        (acc) = fmaxf((acc), fmaxf(fmaxf(s_.x, s_.y), fmaxf(s_.z, s_.w)));    \
    } while (0)

// ---------------------------------------------------------------------------
// Pass 1: exact sequential forward recurrence (the critical path).
// ONE wave. No __syncthreads in the hot loop: a 64-thread block is a single
// wave, the LDS pipe processes a wave's DS ops in issue order, so
// ds_write -> ds_read is correct with just an lgkm fence
// (__threadfence_block == s_waitcnt lgkmcnt(0), no vmcnt drain -> the feats
// prefetch and ckpt stores stay in flight). __launch_bounds__(64,1) gives the
// allocator the full VGPR budget so the 16 f32x4 transition-row registers
// (named, not an array) cannot spill.
// ---------------------------------------------------------------------------
__global__ __launch_bounds__(64, 1) void k_forward(const float* __restrict__ feats,
                                                   const float* __restrict__ trans,
                                                   float* __restrict__ ckpt) {
    const int n = threadIdx.x;
    const f32x4* t4 = reinterpret_cast<const f32x4*>(trans) + (size_t)n * 16;
    const f32x4 q0 = t4[0], q1 = t4[1], q2 = t4[2], q3 = t4[3];
    const f32x4 q4 = t4[4], q5 = t4[5], q6 = t4[6], q7 = t4[7];
    const f32x4 q8 = t4[8], q9 = t4[9], q10 = t4[10], q11 = t4[11];
    const f32x4 q12 = t4[12], q13 = t4[13], q14 = t4[14], q15 = t4[15];

    __shared__ __align__(16) float vsh[L];
    float vreg = (n == STARTT) ? 0.0f : NEGV;
    vsh[n] = vreg;
    __threadfence_block();

    float fc[8];
#pragma unroll
    for (int j = 0; j < 8; ++j) fc[j] = feats[j * L + n];

    for (int tb = 0; tb < TLEN; tb += 8) {
        if ((tb & (CH - 1)) == 0) ckpt[(tb >> 9) * L + n] = vreg;  // v_{tb-1}

        float fn_[8];
        const bool more = (tb + 8) < TLEN;
        if (more) {
#pragma unroll
            for (int j = 0; j < 8; ++j) fn_[j] = feats[(tb + 8 + j) * L + n];
        }
#pragma unroll
        for (int j = 0; j < 8; ++j) {
            float m0 = GRP0(q0, 0), m1 = GRP0(q1, 4), m2 = GRP0(q2, 8), m3 = GRP0(q3, 12);
            GRPA(m0, q4, 16);  GRPA(m1, q5, 20);  GRPA(m2, q6, 24);  GRPA(m3, q7, 28);
            GRPA(m0, q8, 32);  GRPA(m1, q9, 36);  GRPA(m2, q10, 40); GRPA(m3, q11, 44);
            GRPA(m0, q12, 48); GRPA(m1, q13, 52); GRPA(m2, q14, 56); GRPA(m3, q15, 60);
            vreg = fmaxf(fmaxf(m0, m1), fmaxf(m2, m3)) + fc[j];
            vsh[n] = vreg;
            __threadfence_block();
        }
        if (more) {
#pragma unroll
            for (int j = 0; j < 8; ++j) fc[j] = fn_[j];
        }
    }
    ckpt[NCH * L + n] = vreg;  // v_{T-1}
}

// ---------------------------------------------------------------------------
// helpers for the replay kernels (off the critical path)
// ---------------------------------------------------------------------------
__device__ __forceinline__ void load_trow(const float* __restrict__ trans, int n, float* trow) {
#pragma unroll
    for (int i = 0; i < 16; ++i) {
        const f32x4 q = reinterpret_cast<const f32x4*>(trans)[n * 16 + i];
        trow[4 * i + 0] = q.x;
        trow[4 * i + 1] = q.y;
        trow[4 * i + 2] = q.z;
        trow[4 * i + 3] = q.w;
    }
}

// Bit-exact chunk replay from checkpoint; records backpointers into LDS.
// Single wave per block; same fence-instead-of-barrier hot loop as k_forward.
// Argmax uses in-order strictly-greater scans => first-max, matching
// jnp.argmax.
__device__ __forceinline__ void replay_chunk(const float* __restrict__ feats,
                                             const float* __restrict__ ckpt,
                                             const float* trow, float* vsh,
                                             unsigned char* bpl, int c, int len, int n) {
    float vreg = ckpt[c * L + n];
    vsh[n] = vreg;
    __threadfence_block();
    const int base = c * CH;

    float fc[8];
#pragma unroll
    for (int j = 0; j < 8; ++j) fc[j] = feats[(base + j) * L + n];

    for (int sb = 0; sb < len; sb += 8) {
        float fn_[8];
        const bool more = (sb + 8) < len;
        if (more) {
#pragma unroll
            for (int j = 0; j < 8; ++j) fn_[j] = feats[(base + sb + 8 + j) * L + n];
        }
#pragma unroll
        for (int j = 0; j < 8; ++j) {
            float mc[4];
            int ic[4];
#pragma unroll
            for (int g = 0; g < 4; ++g) {
                float m = -INFINITY;
                int idx = g * 16;
#pragma unroll
                for (int r = 0; r < 4; ++r) {
                    const int pb = g * 16 + r * 4;
                    const f32x4 vv = *reinterpret_cast<const f32x4*>(vsh + pb);
                    const float a = vv.x + trow[pb + 0];
                    const float b = vv.y + trow[pb + 1];
                    const float cc = vv.z + trow[pb + 2];
                    const float d = vv.w + trow[pb + 3];
                    if (a > m)  { m = a;  idx = pb + 0; }
                    if (b > m)  { m = b;  idx = pb + 1; }
                    if (cc > m) { m = cc; idx = pb + 2; }
                    if (d > m)  { m = d;  idx = pb + 3; }
                }
                mc[g] = m;
                ic[g] = idx;
            }
            float m = mc[0];
            int idx = ic[0];
            if (mc[1] > m) { m = mc[1]; idx = ic[1]; }
            if (mc[2] > m) { m = mc[2]; idx = ic[2]; }
            if (mc[3] > m) { m = mc[3]; idx = ic[3]; }

            vreg = m + fc[j];
            bpl[(sb + j) * L + n] = (unsigned char)idx;
            vsh[n] = vreg;
            __threadfence_block();
        }
        if (more) {
#pragma unroll
            for (int j = 0; j < 8; ++j) fc[j] = fn_[j];
        }
    }
}

// ---------------------------------------------------------------------------
// Pass 2: per-chunk bit-exact replay -> backpointers -> 64-entry chunk map.
// M[c*64+e] = tag at (c*CH - 1) given tag e at the last step of chunk c.
// ---------------------------------------------------------------------------
__global__ __launch_bounds__(64, 1) void k_maps(const float* __restrict__ feats,
                                                const float* __restrict__ trans,
                                                const float* __restrict__ ckpt,
                                                unsigned char* __restrict__ M) {
    const int c = blockIdx.x;
    const int n = threadIdx.x;
    const int len = (c == NCH - 1) ? LASTLEN : CH;

    __shared__ __align__(16) float vsh[L];
    __shared__ unsigned char bpl[CH * L];

    float trow[L];
    load_trow(trans, n, trow);
    replay_chunk(feats, ckpt, trow, vsh, bpl, c, len, n);
    __syncthreads();

    int tag = n;
    for (int s = len - 1; s >= 0; --s) tag = bpl[s * L + tag];
    M[c * L + n] = (unsigned char)tag;
}

// ---------------------------------------------------------------------------
// Pass 3: terminal argmax (bit-exact score) + back-to-front map composition.
// ---------------------------------------------------------------------------
__global__ __launch_bounds__(64, 1) void k_stitch(const float* __restrict__ trans,
                                                  const float* __restrict__ ckpt,
                                                  const unsigned char* __restrict__ M,
                                                  int* __restrict__ etag,
                                                  float* __restrict__ out) {
    const int n = threadIdx.x;
    __shared__ float tsh[L];
    __shared__ int bsh;
    __shared__ __align__(16) unsigned char msh[NCH * L];

    tsh[n] = ckpt[NCH * L + n] + trans[STOPT * L + n];  // terminal[n]
    __syncthreads();
    if (n == 0) {
        float m = tsh[0];
        int b = 0;
        for (int p = 1; p < L; ++p)
            if (tsh[p] > m) { m = tsh[p]; b = p; }  // first-max, like jnp.argmax
        out[0] = m;   // path_score, bit-exact
        bsh = b;
    }
    __syncthreads();

    for (int i = n; i < (NCH * L) / 4; i += L)
        reinterpret_cast<int*>(msh)[i] = reinterpret_cast<const int*>(M)[i];
    __syncthreads();

    if (n == 0) {
        int carry = bsh;  // tag at t = T-1 = end of chunk NCH-1
        for (int c = NCH - 1; c >= 1; --c) {
            etag[c] = carry;
            carry = msh[c * L + carry];
        }
        etag[0] = carry;
    }
}

// ---------------------------------------------------------------------------
// Pass 4: per-chunk replay again, walk backwards from etag[c], emit path.
// Path written as float32 (harness reads the concatenated output as float).
// ---------------------------------------------------------------------------
__global__ __launch_bounds__(64, 1) void k_emit(const float* __restrict__ feats,
                                                const float* __restrict__ trans,
                                                const float* __restrict__ ckpt,
                                                const int* __restrict__ etag,
                                                float* __restrict__ out) {
    const int c = blockIdx.x;
    const int n = threadIdx.x;
    const int len = (c == NCH - 1) ? LASTLEN : CH;

    __shared__ __align__(16) float vsh[L];
    __shared__ unsigned char bpl[CH * L];
    __shared__ unsigned char plc[CH];

    float trow[L];
    load_trow(trans, n, trow);
    replay_chunk(feats, ckpt, trow, vsh, bpl, c, len, n);
    __syncthreads();

    int tag = etag[c];  // uniform; bpl reads below broadcast (same address)
    for (int s = len - 1; s >= 0; --s) {
        if (n == 0) plc[s] = (unsigned char)tag;
        tag = bpl[s * L + tag];
    }
    __syncthreads();

    for (int i = n; i < len; i += L)
        out[1 + c * CH + i] = (float)plc[i];
}

// ---------------------------------------------------------------------------
extern "C" void kernel_launch(void* const* d_in, const int* in_sizes, int n_in,
                              void* d_out, int out_size, void* d_ws, size_t ws_size,
                              hipStream_t stream) {
    const float* feats = (const float*)d_in[0];   // (1, T, L) fp32
    const float* trans = (const float*)d_in[1];   // (L, L) fp32
    float* out = (float*)d_out;                   // [score, path(T) as float]
    char* ws = (char*)d_ws;
    float* ckpt = (float*)(ws + CKPT_OFF);
    unsigned char* M = (unsigned char*)(ws + M_OFF);
    int* etag = (int*)(ws + ETAG_OFF);

    hipLaunchKernelGGL(k_forward, dim3(1), dim3(64), 0, stream, feats, trans, ckpt);
    hipLaunchKernelGGL(k_maps, dim3(NCH), dim3(64), 0, stream, feats, trans, ckpt, M);
    hipLaunchKernelGGL(k_stitch, dim3(1), dim3(64), 0, stream, trans, ckpt, M, etag, out);
    hipLaunchKernelGGL(k_emit, dim3(NCH), dim3(64), 0, stream, feats, trans, ckpt, etag, out);
}

// Round 3
// 63815.259 us; speedup vs baseline: 1.2477x; 1.0374x over previous
//
#include <hip/hip_runtime.h>

#define L 64
#define TLEN 200000
#define CH 512
#define NCH 391                       // ceil(200000/512)
#define LASTLEN (TLEN - (NCH - 1) * CH)   // 320
#define NEGV -10000.0f
#define STARTT 62
#define STOPT 63

// workspace layout (bytes)
#define CKPT_OFF 0                          // float[(NCH+1)*L]  = 100352 B
#define M_OFF ((NCH + 1) * L * 4)           // uchar[NCH*L]      = 25024 B
#define ETAG_OFF (M_OFF + NCH * L)          // int[NCH]

typedef float f32x4 __attribute__((ext_vector_type(4)));

// Single-wave LDS ping: a 64-thread block is ONE wave and the DS pipe
// processes a wave's LDS ops strictly in order, so ds_write -> ds_read of the
// same address needs NO hardware wait — only a compiler barrier so vsh isn't
// cached/reordered in registers. Zero instructions on the critical chain.
// Side effect (wanted): the memory clobber stops the compiler from
// rematerializing the loop-invariant `trans` loads inside the loop, forcing
// the transition row to stay resident in VGPRs.
#define STEP_BARRIER() __asm__ volatile("" ::: "memory")

// ---------------------------------------------------------------------------
// forward-step group macros: 4 candidates (adds as an f32x4 vector op so the
// backend can select v_pk_add_f32), max tree shaped for v_max3_f32 selection.
// ---------------------------------------------------------------------------
#define GRP0(qq, base)                                                        \
    ({                                                                        \
        const f32x4 va_ = *reinterpret_cast<const f32x4*>(vsh + (base));      \
        const f32x4 s_ = va_ + (qq);                                          \
        fmaxf(fmaxf(s_.x, s_.y), fmaxf(s_.z, s_.w));                          \
    })

#define GRPA(acc, qq, base)                                                   \
    do {                                                                      \
        const f32x4 va_ = *reinterpret_cast<const f32x4*>(vsh + (base));      \
        const f32x4 s_ = va_ + (qq);                                          \
        (acc) = fmaxf((acc), fmaxf(fmaxf(s_.x, s_.y), fmaxf(s_.z, s_.w)));    \
    } while (0)

// ---------------------------------------------------------------------------
// Pass 1: exact sequential forward recurrence (the critical path).
// ONE wave, no barriers, no fences in the hot loop — just compiler barriers.
// ---------------------------------------------------------------------------
__global__ __launch_bounds__(64, 1) void k_forward(const float* __restrict__ feats,
                                                   const float* __restrict__ trans,
                                                   float* __restrict__ ckpt) {
    const int n = threadIdx.x;
    const f32x4* t4 = reinterpret_cast<const f32x4*>(trans) + (size_t)n * 16;
    const f32x4 q0 = t4[0], q1 = t4[1], q2 = t4[2], q3 = t4[3];
    const f32x4 q4 = t4[4], q5 = t4[5], q6 = t4[6], q7 = t4[7];
    const f32x4 q8 = t4[8], q9 = t4[9], q10 = t4[10], q11 = t4[11];
    const f32x4 q12 = t4[12], q13 = t4[13], q14 = t4[14], q15 = t4[15];

    __shared__ __align__(16) float vsh[L];
    float vreg = (n == STARTT) ? 0.0f : NEGV;
    vsh[n] = vreg;
    STEP_BARRIER();

    float fc[8];
#pragma unroll
    for (int j = 0; j < 8; ++j) fc[j] = feats[j * L + n];

    for (int tb = 0; tb < TLEN; tb += 8) {
        if ((tb & (CH - 1)) == 0) ckpt[(tb >> 9) * L + n] = vreg;  // v_{tb-1}

        float fn_[8];
        const bool more = (tb + 8) < TLEN;
        if (more) {
#pragma unroll
            for (int j = 0; j < 8; ++j) fn_[j] = feats[(tb + 8 + j) * L + n];
        }
#pragma unroll
        for (int j = 0; j < 8; ++j) {
            float m0 = GRP0(q0, 0), m1 = GRP0(q1, 4), m2 = GRP0(q2, 8), m3 = GRP0(q3, 12);
            GRPA(m0, q4, 16);  GRPA(m1, q5, 20);  GRPA(m2, q6, 24);  GRPA(m3, q7, 28);
            GRPA(m0, q8, 32);  GRPA(m1, q9, 36);  GRPA(m2, q10, 40); GRPA(m3, q11, 44);
            GRPA(m0, q12, 48); GRPA(m1, q13, 52); GRPA(m2, q14, 56); GRPA(m3, q15, 60);
            vreg = fmaxf(fmaxf(m0, m1), fmaxf(m2, m3)) + fc[j];
            vsh[n] = vreg;
            STEP_BARRIER();
        }
        if (more) {
#pragma unroll
            for (int j = 0; j < 8; ++j) fc[j] = fn_[j];
        }
    }
    ckpt[NCH * L + n] = vreg;  // v_{T-1}
}

// ---------------------------------------------------------------------------
// helpers for the replay kernels (off the critical path)
// ---------------------------------------------------------------------------
__device__ __forceinline__ void load_trow(const float* __restrict__ trans, int n, float* trow) {
#pragma unroll
    for (int i = 0; i < 16; ++i) {
        const f32x4 q = reinterpret_cast<const f32x4*>(trans)[n * 16 + i];
        trow[4 * i + 0] = q.x;
        trow[4 * i + 1] = q.y;
        trow[4 * i + 2] = q.z;
        trow[4 * i + 3] = q.w;
    }
}

// Bit-exact chunk replay from checkpoint; records backpointers into LDS.
// Single wave per block; same compiler-barrier hot loop as k_forward.
// Argmax uses in-order strictly-greater scans => first-max, matching
// jnp.argmax. The max VALUE is order-invariant (exact op), so v matches
// k_forward bit-for-bit.
__device__ __forceinline__ void replay_chunk(const float* __restrict__ feats,
                                             const float* __restrict__ ckpt,
                                             const float* trow, float* vsh,
                                             unsigned char* bpl, int c, int len, int n) {
    float vreg = ckpt[c * L + n];
    vsh[n] = vreg;
    STEP_BARRIER();
    const int base = c * CH;

    float fc[8];
#pragma unroll
    for (int j = 0; j < 8; ++j) fc[j] = feats[(base + j) * L + n];

    for (int sb = 0; sb < len; sb += 8) {
        float fn_[8];
        const bool more = (sb + 8) < len;
        if (more) {
#pragma unroll
            for (int j = 0; j < 8; ++j) fn_[j] = feats[(base + sb + 8 + j) * L + n];
        }
#pragma unroll
        for (int j = 0; j < 8; ++j) {
            float mc[4];
            int ic[4];
#pragma unroll
            for (int g = 0; g < 4; ++g) {
                float m = -INFINITY;
                int idx = g * 16;
#pragma unroll
                for (int r = 0; r < 4; ++r) {
                    const int pb = g * 16 + r * 4;
                    const f32x4 vv = *reinterpret_cast<const f32x4*>(vsh + pb);
                    const float a = vv.x + trow[pb + 0];
                    const float b = vv.y + trow[pb + 1];
                    const float cc = vv.z + trow[pb + 2];
                    const float d = vv.w + trow[pb + 3];
                    if (a > m)  { m = a;  idx = pb + 0; }
                    if (b > m)  { m = b;  idx = pb + 1; }
                    if (cc > m) { m = cc; idx = pb + 2; }
                    if (d > m)  { m = d;  idx = pb + 3; }
                }
                mc[g] = m;
                ic[g] = idx;
            }
            float m = mc[0];
            int idx = ic[0];
            if (mc[1] > m) { m = mc[1]; idx = ic[1]; }
            if (mc[2] > m) { m = mc[2]; idx = ic[2]; }
            if (mc[3] > m) { m = mc[3]; idx = ic[3]; }

            vreg = m + fc[j];
            bpl[(sb + j) * L + n] = (unsigned char)idx;
            vsh[n] = vreg;
            STEP_BARRIER();
        }
        if (more) {
#pragma unroll
            for (int j = 0; j < 8; ++j) fc[j] = fn_[j];
        }
    }
}

// ---------------------------------------------------------------------------
// Pass 2: per-chunk bit-exact replay -> backpointers -> 64-entry chunk map.
// M[c*64+e] = tag at (c*CH - 1) given tag e at the last step of chunk c.
// ---------------------------------------------------------------------------
__global__ __launch_bounds__(64, 1) void k_maps(const float* __restrict__ feats,
                                                const float* __restrict__ trans,
                                                const float* __restrict__ ckpt,
                                                unsigned char* __restrict__ M) {
    const int c = blockIdx.x;
    const int n = threadIdx.x;
    const int len = (c == NCH - 1) ? LASTLEN : CH;

    __shared__ __align__(16) float vsh[L];
    __shared__ unsigned char bpl[CH * L];

    float trow[L];
    load_trow(trans, n, trow);
    replay_chunk(feats, ckpt, trow, vsh, bpl, c, len, n);
    __syncthreads();

    int tag = n;
    for (int s = len - 1; s >= 0; --s) tag = bpl[s * L + tag];
    M[c * L + n] = (unsigned char)tag;
}

// ---------------------------------------------------------------------------
// Pass 3: terminal argmax (bit-exact score) + back-to-front map composition.
// ---------------------------------------------------------------------------
__global__ __launch_bounds__(64, 1) void k_stitch(const float* __restrict__ trans,
                                                  const float* __restrict__ ckpt,
                                                  const unsigned char* __restrict__ M,
                                                  int* __restrict__ etag,
                                                  float* __restrict__ out) {
    const int n = threadIdx.x;
    __shared__ float tsh[L];
    __shared__ int bsh;
    __shared__ __align__(16) unsigned char msh[NCH * L];

    tsh[n] = ckpt[NCH * L + n] + trans[STOPT * L + n];  // terminal[n]
    __syncthreads();
    if (n == 0) {
        float m = tsh[0];
        int b = 0;
        for (int p = 1; p < L; ++p)
            if (tsh[p] > m) { m = tsh[p]; b = p; }  // first-max, like jnp.argmax
        out[0] = m;   // path_score, bit-exact
        bsh = b;
    }
    __syncthreads();

    for (int i = n; i < (NCH * L) / 4; i += L)
        reinterpret_cast<int*>(msh)[i] = reinterpret_cast<const int*>(M)[i];
    __syncthreads();

    if (n == 0) {
        int carry = bsh;  // tag at t = T-1 = end of chunk NCH-1
        for (int c = NCH - 1; c >= 1; --c) {
            etag[c] = carry;
            carry = msh[c * L + carry];
        }
        etag[0] = carry;
    }
}

// ---------------------------------------------------------------------------
// Pass 4: per-chunk replay again, walk backwards from etag[c], emit path.
// Path written as float32 (harness reads the concatenated output as float).
// ---------------------------------------------------------------------------
__global__ __launch_bounds__(64, 1) void k_emit(const float* __restrict__ feats,
                                                const float* __restrict__ trans,
                                                const float* __restrict__ ckpt,
                                                const int* __restrict__ etag,
                                                float* __restrict__ out) {
    const int c = blockIdx.x;
    const int n = threadIdx.x;
    const int len = (c == NCH - 1) ? LASTLEN : CH;

    __shared__ __align__(16) float vsh[L];
    __shared__ unsigned char bpl[CH * L];
    __shared__ unsigned char plc[CH];

    float trow[L];
    load_trow(trans, n, trow);
    replay_chunk(feats, ckpt, trow, vsh, bpl, c, len, n);
    __syncthreads();

    int tag = etag[c];  // uniform; bpl reads below broadcast (same address)
    for (int s = len - 1; s >= 0; --s) {
        if (n == 0) plc[s] = (unsigned char)tag;
        tag = bpl[s * L + tag];
    }
    __syncthreads();

    for (int i = n; i < len; i += L)
        out[1 + c * CH + i] = (float)plc[i];
}

// ---------------------------------------------------------------------------
extern "C" void kernel_launch(void* const* d_in, const int* in_sizes, int n_in,
                              void* d_out, int out_size, void* d_ws, size_t ws_size,
                              hipStream_t stream) {
    const float* feats = (const float*)d_in[0];   // (1, T, L) fp32
    const float* trans = (const float*)d_in[1];   // (L, L) fp32
    float* out = (float*)d_out;                   // [score, path(T) as float]
    char* ws = (char*)d_ws;
    float* ckpt = (float*)(ws + CKPT_OFF);
    unsigned char* M = (unsigned char*)(ws + M_OFF);
    int* etag = (int*)(ws + ETAG_OFF);

    hipLaunchKernelGGL(k_forward, dim3(1), dim3(64), 0, stream, feats, trans, ckpt);
    hipLaunchKernelGGL(k_maps, dim3(NCH), dim3(64), 0, stream, feats, trans, ckpt, M);
    hipLaunchKernelGGL(k_stitch, dim3(1), dim3(64), 0, stream, trans, ckpt, M, etag, out);
    hipLaunchKernelGGL(k_emit, dim3(NCH), dim3(64), 0, stream, feats, trans, ckpt, etag, out);
}

// Round 4
// 62822.009 us; speedup vs baseline: 1.2674x; 1.0158x over previous
//
#include <hip/hip_runtime.h>

#define L 64
#define TLEN 200000
#define CH 512
#define NCH 391                       // ceil(200000/512)
#define LASTLEN (TLEN - (NCH - 1) * CH)   // 320
#define NEGV -10000.0f
#define STARTT 62
#define STOPT 63

// workspace layout (bytes)
#define CKPT_OFF 0                          // float[(NCH+1)*L]  = 100352 B
#define M_OFF ((NCH + 1) * L * 4)           // uchar[NCH*L]      = 25024 B
#define ETAG_OFF (M_OFF + NCH * L)          // int[NCH]

typedef float f32x4 __attribute__((ext_vector_type(4)));

// Single-wave LDS ping: a 64-thread block is ONE wave and the DS pipe
// processes a wave's LDS ops strictly in order, so ds_write -> ds_read of the
// same address needs NO hardware wait — only a compiler barrier so vsh isn't
// cached/reordered in registers. Zero instructions on the critical chain.
#define STEP_BARRIER() __asm__ volatile("" ::: "memory")

// Remat-proof register pinning: make the values outputs of an opaque volatile
// asm. The register allocator can rematerialize an invariant LOAD at its use
// site (which is what kept VGPR_Count at 52 and re-issued 16
// global_load_dwordx4 per step), but it cannot recompute an asm result —
// the 64 floats of the transition row must stay resident in VGPRs.
#define PIN8(a, b, c, d, e, f, g, h)                                          \
    __asm__ volatile("" : "+v"(a), "+v"(b), "+v"(c), "+v"(d),                 \
                          "+v"(e), "+v"(f), "+v"(g), "+v"(h))

// ---------------------------------------------------------------------------
// forward-step group macros: 4 candidates (adds as an f32x4 vector op so the
// backend can select v_pk_add_f32), max tree shaped for v_max3_f32 selection.
// ---------------------------------------------------------------------------
#define GRP0(qq, base)                                                        \
    ({                                                                        \
        const f32x4 va_ = *reinterpret_cast<const f32x4*>(vsh + (base));      \
        const f32x4 s_ = va_ + (qq);                                          \
        fmaxf(fmaxf(s_.x, s_.y), fmaxf(s_.z, s_.w));                          \
    })

#define GRPA(acc, qq, base)                                                   \
    do {                                                                      \
        const f32x4 va_ = *reinterpret_cast<const f32x4*>(vsh + (base));      \
        const f32x4 s_ = va_ + (qq);                                          \
        (acc) = fmaxf((acc), fmaxf(fmaxf(s_.x, s_.y), fmaxf(s_.z, s_.w)));    \
    } while (0)

// ---------------------------------------------------------------------------
// Pass 1: exact sequential forward recurrence (the critical path).
// ONE wave, no barriers/fences in the hot loop — just compiler barriers and
// pinned transition-row registers.
// ---------------------------------------------------------------------------
__global__ __launch_bounds__(64, 1) void k_forward(const float* __restrict__ feats,
                                                   const float* __restrict__ trans,
                                                   float* __restrict__ ckpt) {
    const int n = threadIdx.x;
    const f32x4* t4 = reinterpret_cast<const f32x4*>(trans) + (size_t)n * 16;
    f32x4 q0 = t4[0], q1 = t4[1], q2 = t4[2], q3 = t4[3];
    f32x4 q4 = t4[4], q5 = t4[5], q6 = t4[6], q7 = t4[7];
    f32x4 q8 = t4[8], q9 = t4[9], q10 = t4[10], q11 = t4[11];
    f32x4 q12 = t4[12], q13 = t4[13], q14 = t4[14], q15 = t4[15];
    PIN8(q0, q1, q2, q3, q4, q5, q6, q7);
    PIN8(q8, q9, q10, q11, q12, q13, q14, q15);

    __shared__ __align__(16) float vsh[L];
    float vreg = (n == STARTT) ? 0.0f : NEGV;
    vsh[n] = vreg;
    STEP_BARRIER();

    float fc[8];
#pragma unroll
    for (int j = 0; j < 8; ++j) fc[j] = feats[j * L + n];

    for (int tb = 0; tb < TLEN; tb += 8) {
        if ((tb & (CH - 1)) == 0) ckpt[(tb >> 9) * L + n] = vreg;  // v_{tb-1}

        float fn_[8];
        const bool more = (tb + 8) < TLEN;
        if (more) {
#pragma unroll
            for (int j = 0; j < 8; ++j) fn_[j] = feats[(tb + 8 + j) * L + n];
        }
#pragma unroll
        for (int j = 0; j < 8; ++j) {
            float m0 = GRP0(q0, 0), m1 = GRP0(q1, 4), m2 = GRP0(q2, 8), m3 = GRP0(q3, 12);
            GRPA(m0, q4, 16);  GRPA(m1, q5, 20);  GRPA(m2, q6, 24);  GRPA(m3, q7, 28);
            GRPA(m0, q8, 32);  GRPA(m1, q9, 36);  GRPA(m2, q10, 40); GRPA(m3, q11, 44);
            GRPA(m0, q12, 48); GRPA(m1, q13, 52); GRPA(m2, q14, 56); GRPA(m3, q15, 60);
            vreg = fmaxf(fmaxf(m0, m1), fmaxf(m2, m3)) + fc[j];
            vsh[n] = vreg;
            STEP_BARRIER();
        }
        if (more) {
#pragma unroll
            for (int j = 0; j < 8; ++j) fc[j] = fn_[j];
        }
    }
    ckpt[NCH * L + n] = vreg;  // v_{T-1}
}

// ---------------------------------------------------------------------------
// helpers for the replay kernels (off the critical path)
// ---------------------------------------------------------------------------
__device__ __forceinline__ void load_trow(const float* __restrict__ trans, int n, float* trow) {
#pragma unroll
    for (int i = 0; i < 16; ++i) {
        const f32x4 q = reinterpret_cast<const f32x4*>(trans)[n * 16 + i];
        trow[4 * i + 0] = q.x;
        trow[4 * i + 1] = q.y;
        trow[4 * i + 2] = q.z;
        trow[4 * i + 3] = q.w;
    }
}

// Bit-exact chunk replay from checkpoint; records backpointers into LDS.
// Single wave per block; same compiler-barrier hot loop as k_forward.
// Argmax uses in-order strictly-greater scans => first-max, matching
// jnp.argmax. The max VALUE is order-invariant (exact op), so v matches
// k_forward bit-for-bit.
__device__ __forceinline__ void replay_chunk(const float* __restrict__ feats,
                                             const float* __restrict__ ckpt,
                                             const float* trow, float* vsh,
                                             unsigned char* bpl, int c, int len, int n) {
    float vreg = ckpt[c * L + n];
    vsh[n] = vreg;
    STEP_BARRIER();
    const int base = c * CH;

    float fc[8];
#pragma unroll
    for (int j = 0; j < 8; ++j) fc[j] = feats[(base + j) * L + n];

    for (int sb = 0; sb < len; sb += 8) {
        float fn_[8];
        const bool more = (sb + 8) < len;
        if (more) {
#pragma unroll
            for (int j = 0; j < 8; ++j) fn_[j] = feats[(base + sb + 8 + j) * L + n];
        }
#pragma unroll
        for (int j = 0; j < 8; ++j) {
            float mc[4];
            int ic[4];
#pragma unroll
            for (int g = 0; g < 4; ++g) {
                float m = -INFINITY;
                int idx = g * 16;
#pragma unroll
                for (int r = 0; r < 4; ++r) {
                    const int pb = g * 16 + r * 4;
                    const f32x4 vv = *reinterpret_cast<const f32x4*>(vsh + pb);
                    const float a = vv.x + trow[pb + 0];
                    const float b = vv.y + trow[pb + 1];
                    const float cc = vv.z + trow[pb + 2];
                    const float d = vv.w + trow[pb + 3];
                    if (a > m)  { m = a;  idx = pb + 0; }
                    if (b > m)  { m = b;  idx = pb + 1; }
                    if (cc > m) { m = cc; idx = pb + 2; }
                    if (d > m)  { m = d;  idx = pb + 3; }
                }
                mc[g] = m;
                ic[g] = idx;
            }
            float m = mc[0];
            int idx = ic[0];
            if (mc[1] > m) { m = mc[1]; idx = ic[1]; }
            if (mc[2] > m) { m = mc[2]; idx = ic[2]; }
            if (mc[3] > m) { m = mc[3]; idx = ic[3]; }

            vreg = m + fc[j];
            bpl[(sb + j) * L + n] = (unsigned char)idx;
            vsh[n] = vreg;
            STEP_BARRIER();
        }
        if (more) {
#pragma unroll
            for (int j = 0; j < 8; ++j) fc[j] = fn_[j];
        }
    }
}

// ---------------------------------------------------------------------------
// Pass 2: per-chunk bit-exact replay -> backpointers -> 64-entry chunk map.
// M[c*64+e] = tag at (c*CH - 1) given tag e at the last step of chunk c.
// ---------------------------------------------------------------------------
__global__ __launch_bounds__(64, 1) void k_maps(const float* __restrict__ feats,
                                                const float* __restrict__ trans,
                                                const float* __restrict__ ckpt,
                                                unsigned char* __restrict__ M) {
    const int c = blockIdx.x;
    const int n = threadIdx.x;
    const int len = (c == NCH - 1) ? LASTLEN : CH;

    __shared__ __align__(16) float vsh[L];
    __shared__ unsigned char bpl[CH * L];

    float trow[L];
    load_trow(trans, n, trow);
    replay_chunk(feats, ckpt, trow, vsh, bpl, c, len, n);
    __syncthreads();

    int tag = n;
    for (int s = len - 1; s >= 0; --s) tag = bpl[s * L + tag];
    M[c * L + n] = (unsigned char)tag;
}

// ---------------------------------------------------------------------------
// Pass 3: terminal argmax (bit-exact score) + back-to-front map composition.
// ---------------------------------------------------------------------------
__global__ __launch_bounds__(64, 1) void k_stitch(const float* __restrict__ trans,
                                                  const float* __restrict__ ckpt,
                                                  const unsigned char* __restrict__ M,
                                                  int* __restrict__ etag,
                                                  float* __restrict__ out) {
    const int n = threadIdx.x;
    __shared__ float tsh[L];
    __shared__ int bsh;
    __shared__ __align__(16) unsigned char msh[NCH * L];

    tsh[n] = ckpt[NCH * L + n] + trans[STOPT * L + n];  // terminal[n]
    __syncthreads();
    if (n == 0) {
        float m = tsh[0];
        int b = 0;
        for (int p = 1; p < L; ++p)
            if (tsh[p] > m) { m = tsh[p]; b = p; }  // first-max, like jnp.argmax
        out[0] = m;   // path_score, bit-exact
        bsh = b;
    }
    __syncthreads();

    for (int i = n; i < (NCH * L) / 4; i += L)
        reinterpret_cast<int*>(msh)[i] = reinterpret_cast<const int*>(M)[i];
    __syncthreads();

    if (n == 0) {
        int carry = bsh;  // tag at t = T-1 = end of chunk NCH-1
        for (int c = NCH - 1; c >= 1; --c) {
            etag[c] = carry;
            carry = msh[c * L + carry];
        }
        etag[0] = carry;
    }
}

// ---------------------------------------------------------------------------
// Pass 4: per-chunk replay again, walk backwards from etag[c], emit path.
// Path written as float32 (harness reads the concatenated output as float).
// ---------------------------------------------------------------------------
__global__ __launch_bounds__(64, 1) void k_emit(const float* __restrict__ feats,
                                                const float* __restrict__ trans,
                                                const float* __restrict__ ckpt,
                                                const int* __restrict__ etag,
                                                float* __restrict__ out) {
    const int c = blockIdx.x;
    const int n = threadIdx.x;
    const int len = (c == NCH - 1) ? LASTLEN : CH;

    __shared__ __align__(16) float vsh[L];
    __shared__ unsigned char bpl[CH * L];
    __shared__ unsigned char plc[CH];

    float trow[L];
    load_trow(trans, n, trow);
    replay_chunk(feats, ckpt, trow, vsh, bpl, c, len, n);
    __syncthreads();

    int tag = etag[c];  // uniform; bpl reads below broadcast (same address)
    for (int s = len - 1; s >= 0; --s) {
        if (n == 0) plc[s] = (unsigned char)tag;
        tag = bpl[s * L + tag];
    }
    __syncthreads();

    for (int i = n; i < len; i += L)
        out[1 + c * CH + i] = (float)plc[i];
}

// ---------------------------------------------------------------------------
extern "C" void kernel_launch(void* const* d_in, const int* in_sizes, int n_in,
                              void* d_out, int out_size, void* d_ws, size_t ws_size,
                              hipStream_t stream) {
    const float* feats = (const float*)d_in[0];   // (1, T, L) fp32
    const float* trans = (const float*)d_in[1];   // (L, L) fp32
    float* out = (float*)d_out;                   // [score, path(T) as float]
    char* ws = (char*)d_ws;
    float* ckpt = (float*)(ws + CKPT_OFF);
    unsigned char* M = (unsigned char*)(ws + M_OFF);
    int* etag = (int*)(ws + ETAG_OFF);

    hipLaunchKernelGGL(k_forward, dim3(1), dim3(64), 0, stream, feats, trans, ckpt);
    hipLaunchKernelGGL(k_maps, dim3(NCH), dim3(64), 0, stream, feats, trans, ckpt, M);
    hipLaunchKernelGGL(k_stitch, dim3(1), dim3(64), 0, stream, trans, ckpt, M, etag, out);
    hipLaunchKernelGGL(k_emit, dim3(NCH), dim3(64), 0, stream, feats, trans, ckpt, etag, out);
}

// Round 5
// 33141.492 us; speedup vs baseline: 2.4025x; 1.8956x over previous
//
#include <hip/hip_runtime.h>

#define L 64
#define TLEN 200000
#define CH 528                        // divisible by 6 (fwd unroll) and 8 (replay unroll)
#define NCH 379                       // ceil(200000/528); 378*528 = 199584
#define LASTLEN (TLEN - (NCH - 1) * CH)   // 416 (divisible by 8)
#define MAINT 199992                  // 6*33332, main-loop trip; tail = 8 steps
#define NEGV -10000.0f
#define STARTT 62
#define STOPT 63

// workspace layout (bytes) — total 123052 < 126940 proven available
#define CKPT_OFF 0                          // float[(NCH+1)*L]  = 97280 B
#define M_OFF ((NCH + 1) * L * 4)           // uchar[NCH*L]      = 24256 B
#define ETAG_OFF (M_OFF + NCH * L)          // int[NCH]          = 1516 B

typedef float f32x4 __attribute__((ext_vector_type(4)));

// Cross-wave step barrier WITHOUT vmcnt drain: LDS ops (incl. atomics) are
// covered by lgkmcnt; feats prefetch (vmcnt) stays in flight across steps.
#define WAVE_BARRIER() __asm__ volatile("s_waitcnt lgkmcnt(0)\ns_barrier" ::: "memory")
#define STEP_BARRIER() __asm__ volatile("" ::: "memory")

// ---------------------------------------------------------------------------
// Pass 1: exact sequential forward recurrence (the critical path).
// 4 waves (256 threads), p-split: wave w owns prev-tags [16w,16w+16).
// Each step: broadcast-read own v-slice, partial max, +feat (exact: RN is
// monotone so max_w RN(pm_w+f) == RN(max pm + f)), ds_max_f32 atomic into the
// next v-buffer, one barrier. Triple-buffered v: step s reads buf s%3,
// atomics into (s+1)%3, wave0 resets (s+2)%3 to -inf. The single barrier
// orders all hazards: resets of buf B precede the barrier that precedes any
// atomic into B; reads of B complete before the barrier that precedes any
// reset of B.
// ---------------------------------------------------------------------------
__global__ __launch_bounds__(256, 1) void k_forward(const float* __restrict__ feats,
                                                    const float* __restrict__ trans,
                                                    float* __restrict__ ckpt) {
    const int tid = threadIdx.x;
    const int n = tid & 63;   // next-tag owned by this lane
    const int w = tid >> 6;   // wave id = p-slice

    // T[n][16w .. 16w+16) — 16 floats, 4 quads, no register pressure
    const f32x4* t4 = reinterpret_cast<const f32x4*>(trans) + n * 16 + w * 4;
    f32x4 q0 = t4[0], q1 = t4[1], q2 = t4[2], q3 = t4[3];
    __asm__ volatile("" : "+v"(q0), "+v"(q1), "+v"(q2), "+v"(q3));

    __shared__ __align__(16) float vbuf[3][L];

    vbuf[0][n] = (n == STARTT) ? 0.0f : NEGV;  // v_{-1}; same value from all waves
    vbuf[1][n] = -INFINITY;                    // receives step-0 atomics
    vbuf[2][n] = -INFINITY;
    WAVE_BARRIER();

    float fc[6];
#pragma unroll
    for (int j = 0; j < 6; ++j) fc[j] = feats[j * L + n];

    int nextck = 0, cidx = 0;

#define FWD_STEP(RD, WR, RS, FEAT)                                            \
    do {                                                                      \
        if (w == 0) vbuf[RS][n] = -INFINITY;                                  \
        const f32x4 va0 = *reinterpret_cast<const f32x4*>(&vbuf[RD][16 * w + 0]);  \
        const f32x4 va1 = *reinterpret_cast<const f32x4*>(&vbuf[RD][16 * w + 4]);  \
        const f32x4 va2 = *reinterpret_cast<const f32x4*>(&vbuf[RD][16 * w + 8]);  \
        const f32x4 va3 = *reinterpret_cast<const f32x4*>(&vbuf[RD][16 * w + 12]); \
        const f32x4 s0 = va0 + q0, s1 = va1 + q1, s2 = va2 + q2, s3 = va3 + q3;    \
        const float m0 = fmaxf(fmaxf(s0.x, s0.y), fmaxf(s0.z, s0.w));         \
        const float m1 = fmaxf(fmaxf(s1.x, s1.y), fmaxf(s1.z, s1.w));         \
        const float m2 = fmaxf(fmaxf(s2.x, s2.y), fmaxf(s2.z, s2.w));         \
        const float m3 = fmaxf(fmaxf(s3.x, s3.y), fmaxf(s3.z, s3.w));         \
        const float cand = fmaxf(fmaxf(m0, m1), fmaxf(m2, m3)) + (FEAT);      \
        __hip_atomic_fetch_max(&vbuf[WR][n], cand, __ATOMIC_RELAXED,          \
                               __HIP_MEMORY_SCOPE_WORKGROUP);                 \
        WAVE_BARRIER();                                                       \
    } while (0)

    for (int tb = 0; tb < MAINT; tb += 6) {
        if (tb == nextck) {
            // vbuf[0] holds v_{tb-1} (tb%3==0 always; 528%6==0 keeps hits aligned)
            if (w == 0) ckpt[cidx * L + n] = vbuf[0][n];
            nextck += CH;
            ++cidx;
        }
        float fn_[6];
        const bool more = (tb + 6) < MAINT;
        if (more) {
#pragma unroll
            for (int j = 0; j < 6; ++j) fn_[j] = feats[(tb + 6 + j) * L + n];
        }
        FWD_STEP(0, 1, 2, fc[0]);
        FWD_STEP(1, 2, 0, fc[1]);
        FWD_STEP(2, 0, 1, fc[2]);
        FWD_STEP(0, 1, 2, fc[3]);
        FWD_STEP(1, 2, 0, fc[4]);
        FWD_STEP(2, 0, 1, fc[5]);
        if (more) {
#pragma unroll
            for (int j = 0; j < 6; ++j) fc[j] = fn_[j];
        }
    }

    // tail: steps 199992..199999 (MAINT%3==0, so the rotation continues)
    float ft[8];
#pragma unroll
    for (int j = 0; j < 8; ++j) ft[j] = feats[(MAINT + j) * L + n];
    FWD_STEP(0, 1, 2, ft[0]);
    FWD_STEP(1, 2, 0, ft[1]);
    FWD_STEP(2, 0, 1, ft[2]);
    FWD_STEP(0, 1, 2, ft[3]);
    FWD_STEP(1, 2, 0, ft[4]);
    FWD_STEP(2, 0, 1, ft[5]);
    FWD_STEP(0, 1, 2, ft[6]);
    FWD_STEP(1, 2, 0, ft[7]);
    // v_{199999} lives in vbuf[200000 % 3] = vbuf[2]
    if (w == 0) ckpt[NCH * L + n] = vbuf[2][n];
#undef FWD_STEP
}

// ---------------------------------------------------------------------------
// helpers for the replay kernels (off the critical path, ~1.3 ms total)
// ---------------------------------------------------------------------------
__device__ __forceinline__ void load_trow(const float* __restrict__ trans, int n, float* trow) {
#pragma unroll
    for (int i = 0; i < 16; ++i) {
        const f32x4 q = reinterpret_cast<const f32x4*>(trans)[n * 16 + i];
        trow[4 * i + 0] = q.x;
        trow[4 * i + 1] = q.y;
        trow[4 * i + 2] = q.z;
        trow[4 * i + 3] = q.w;
    }
}

// Bit-exact chunk replay from checkpoint; records backpointers into LDS.
// Single wave per block; in-order DS pipe makes ds_write->ds_read safe with
// only a compiler barrier. Argmax is an in-order strictly-greater scan =>
// first-max, matching jnp.argmax; v matches k_forward bit-for-bit (max is
// order-invariant, +feat monotone-exact).
__device__ __forceinline__ void replay_chunk(const float* __restrict__ feats,
                                             const float* __restrict__ ckpt,
                                             const float* trow, float* vsh,
                                             unsigned char* bpl, int c, int len, int n) {
    float vreg = ckpt[c * L + n];
    vsh[n] = vreg;
    STEP_BARRIER();
    const int base = c * CH;

    float fc[8];
#pragma unroll
    for (int j = 0; j < 8; ++j) fc[j] = feats[(base + j) * L + n];

    for (int sb = 0; sb < len; sb += 8) {
        float fn_[8];
        const bool more = (sb + 8) < len;
        if (more) {
#pragma unroll
            for (int j = 0; j < 8; ++j) fn_[j] = feats[(base + sb + 8 + j) * L + n];
        }
#pragma unroll
        for (int j = 0; j < 8; ++j) {
            float mc[4];
            int ic[4];
#pragma unroll
            for (int g = 0; g < 4; ++g) {
                float m = -INFINITY;
                int idx = g * 16;
#pragma unroll
                for (int r = 0; r < 4; ++r) {
                    const int pb = g * 16 + r * 4;
                    const f32x4 vv = *reinterpret_cast<const f32x4*>(vsh + pb);
                    const float a = vv.x + trow[pb + 0];
                    const float b = vv.y + trow[pb + 1];
                    const float cc = vv.z + trow[pb + 2];
                    const float d = vv.w + trow[pb + 3];
                    if (a > m)  { m = a;  idx = pb + 0; }
                    if (b > m)  { m = b;  idx = pb + 1; }
                    if (cc > m) { m = cc; idx = pb + 2; }
                    if (d > m)  { m = d;  idx = pb + 3; }
                }
                mc[g] = m;
                ic[g] = idx;
            }
            float m = mc[0];
            int idx = ic[0];
            if (mc[1] > m) { m = mc[1]; idx = ic[1]; }
            if (mc[2] > m) { m = mc[2]; idx = ic[2]; }
            if (mc[3] > m) { m = mc[3]; idx = ic[3]; }

            vreg = m + fc[j];
            bpl[(sb + j) * L + n] = (unsigned char)idx;
            vsh[n] = vreg;
            STEP_BARRIER();
        }
        if (more) {
#pragma unroll
            for (int j = 0; j < 8; ++j) fc[j] = fn_[j];
        }
    }
}

// ---------------------------------------------------------------------------
// Pass 2: per-chunk bit-exact replay -> backpointers -> 64-entry chunk map.
// M[c*64+e] = tag at (c*CH - 1) given tag e at the last step of chunk c.
// ---------------------------------------------------------------------------
__global__ __launch_bounds__(64, 1) void k_maps(const float* __restrict__ feats,
                                                const float* __restrict__ trans,
                                                const float* __restrict__ ckpt,
                                                unsigned char* __restrict__ M) {
    const int c = blockIdx.x;
    const int n = threadIdx.x;
    const int len = (c == NCH - 1) ? LASTLEN : CH;

    __shared__ __align__(16) float vsh[L];
    __shared__ unsigned char bpl[CH * L];

    float trow[L];
    load_trow(trans, n, trow);
    replay_chunk(feats, ckpt, trow, vsh, bpl, c, len, n);
    __syncthreads();

    int tag = n;
    for (int s = len - 1; s >= 0; --s) tag = bpl[s * L + tag];
    M[c * L + n] = (unsigned char)tag;
}

// ---------------------------------------------------------------------------
// Pass 3: terminal argmax (bit-exact score) + back-to-front map composition.
// ---------------------------------------------------------------------------
__global__ __launch_bounds__(64, 1) void k_stitch(const float* __restrict__ trans,
                                                  const float* __restrict__ ckpt,
                                                  const unsigned char* __restrict__ M,
                                                  int* __restrict__ etag,
                                                  float* __restrict__ out) {
    const int n = threadIdx.x;
    __shared__ float tsh[L];
    __shared__ int bsh;
    __shared__ __align__(16) unsigned char msh[NCH * L];

    tsh[n] = ckpt[NCH * L + n] + trans[STOPT * L + n];  // terminal[n]
    __syncthreads();
    if (n == 0) {
        float m = tsh[0];
        int b = 0;
        for (int p = 1; p < L; ++p)
            if (tsh[p] > m) { m = tsh[p]; b = p; }  // first-max, like jnp.argmax
        out[0] = m;   // path_score, bit-exact
        bsh = b;
    }
    __syncthreads();

    for (int i = n; i < (NCH * L) / 4; i += L)
        reinterpret_cast<int*>(msh)[i] = reinterpret_cast<const int*>(M)[i];
    __syncthreads();

    if (n == 0) {
        int carry = bsh;  // tag at t = T-1 = end of chunk NCH-1
        for (int c = NCH - 1; c >= 1; --c) {
            etag[c] = carry;
            carry = msh[c * L + carry];
        }
        etag[0] = carry;
    }
}

// ---------------------------------------------------------------------------
// Pass 4: per-chunk replay again, walk backwards from etag[c], emit path.
// Path written as float32 (harness reads the concatenated output as float).
// ---------------------------------------------------------------------------
__global__ __launch_bounds__(64, 1) void k_emit(const float* __restrict__ feats,
                                                const float* __restrict__ trans,
                                                const float* __restrict__ ckpt,
                                                const int* __restrict__ etag,
                                                float* __restrict__ out) {
    const int c = blockIdx.x;
    const int n = threadIdx.x;
    const int len = (c == NCH - 1) ? LASTLEN : CH;

    __shared__ __align__(16) float vsh[L];
    __shared__ unsigned char bpl[CH * L];
    __shared__ unsigned char plc[CH];

    float trow[L];
    load_trow(trans, n, trow);
    replay_chunk(feats, ckpt, trow, vsh, bpl, c, len, n);
    __syncthreads();

    int tag = etag[c];  // uniform; bpl reads below broadcast (same address)
    for (int s = len - 1; s >= 0; --s) {
        if (n == 0) plc[s] = (unsigned char)tag;
        tag = bpl[s * L + tag];
    }
    __syncthreads();

    for (int i = n; i < len; i += L)
        out[1 + c * CH + i] = (float)plc[i];
}

// ---------------------------------------------------------------------------
extern "C" void kernel_launch(void* const* d_in, const int* in_sizes, int n_in,
                              void* d_out, int out_size, void* d_ws, size_t ws_size,
                              hipStream_t stream) {
    const float* feats = (const float*)d_in[0];   // (1, T, L) fp32
    const float* trans = (const float*)d_in[1];   // (L, L) fp32
    float* out = (float*)d_out;                   // [score, path(T) as float]
    char* ws = (char*)d_ws;
    float* ckpt = (float*)(ws + CKPT_OFF);
    unsigned char* M = (unsigned char*)(ws + M_OFF);
    int* etag = (int*)(ws + ETAG_OFF);

    hipLaunchKernelGGL(k_forward, dim3(1), dim3(256), 0, stream, feats, trans, ckpt);
    hipLaunchKernelGGL(k_maps, dim3(NCH), dim3(64), 0, stream, feats, trans, ckpt, M);
    hipLaunchKernelGGL(k_stitch, dim3(1), dim3(64), 0, stream, trans, ckpt, M, etag, out);
    hipLaunchKernelGGL(k_emit, dim3(NCH), dim3(64), 0, stream, feats, trans, ckpt, etag, out);
}